// Round 3
// baseline (787.620 us; speedup 1.0000x reference)
//
#include <hip/hip_runtime.h>

#define CI 4
#define CO 8
#define TT 8
#define S 96
#define SLICE (S*S*S)          // 884736 elements per (c,t) slice
#define NSLICE (CI*TT)         // 32 slices
#define EPS 1e-5f
#define WTOT (CO*CI*81)        // 10368 weight elements
#define WS_WT_OFF 64           // float offset of transposed weights in ws

// ws layout (floats): [0:32) sum, [32:64) sumsq, [64:64+WTOT) transposed weights

__global__ __launch_bounds__(256) void stats_partial(
        const float* __restrict__ x, float* __restrict__ ws) {
    const int slice = blockIdx.y;
    const float4* p = reinterpret_cast<const float4*>(x + (size_t)slice * SLICE);
    const int n4 = SLICE / 4;  // 221184
    float s = 0.f, ss = 0.f;
    for (int i = blockIdx.x * blockDim.x + threadIdx.x; i < n4;
         i += gridDim.x * blockDim.x) {
        float4 v = p[i];
        s  += v.x + v.y + v.z + v.w;
        ss += v.x*v.x + v.y*v.y + v.z*v.z + v.w*v.w;
    }
    #pragma unroll
    for (int off = 32; off > 0; off >>= 1) {
        s  += __shfl_down(s, off);
        ss += __shfl_down(ss, off);
    }
    __shared__ float ls[4], lss[4];
    const int lane = threadIdx.x & 63, wid = threadIdx.x >> 6;
    if (lane == 0) { ls[wid] = s; lss[wid] = ss; }
    __syncthreads();
    if (threadIdx.x == 0) {
        float ts  = ls[0] + ls[1] + ls[2] + ls[3];
        float tss = lss[0] + lss[1] + lss[2] + lss[3];
        atomicAdd(&ws[slice], ts);
        atomicAdd(&ws[NSLICE + slice], tss);
    }
}

// Transpose weights (CO,CI,3,3,3,3) -> [ci][kt][kd][kh][co][kw] so each
// (kd,kh) tap group is 24 contiguous floats (96 B) => wide s_loads.
__global__ void wtranspose(const float* __restrict__ w, float* __restrict__ wt) {
    int i = blockIdx.x * blockDim.x + threadIdx.x;
    if (i >= WTOT) return;
    int kw = i % 3; int r = i / 3;
    int co = r % CO; r /= CO;
    int kh = r % 3;  r /= 3;
    int kd = r % 3;  r /= 3;
    int kt = r % 3;  r /= 3;
    int ci = r;
    wt[i] = w[((((co * CI + ci) * 3 + kt) * 3 + kd) * 3 + kh) * 3 + kw];
}

__device__ __forceinline__ void load_rows(
        const float* __restrict__ xp, int h0, int w0, int om1, int op4,
        float4 f4[4], float e0[4], float e1[4]) {
    #pragma unroll
    for (int r = 0; r < 4; r++) {
        const int hh = h0 + r - 1;
        const int hc = hh < 0 ? 0 : (hh > S - 1 ? S - 1 : hh);
        const float* row = xp + hc * S + w0;
        f4[r] = *reinterpret_cast<const float4*>(row);
        e0[r] = row[om1];
        e1[r] = row[op4];
    }
}

// Normalize 4 raw rows and apply the 6 (P,KH) tap sets of one kd.
// TW: wp points at 72 contiguous floats [kh][co][kw].
// !TW: wp = wgt + ci*81 + kt*27 + kd*9; weights at wp + co*324 + kh*3.
template <bool TW>
__device__ __forceinline__ void compute_kd(
        const float4 f4[4], const float e0[4], const float e1[4],
        float rstd, float nmr, float md, int h0, float fwl, float fwr,
        const float* __restrict__ wp, float acc[2][CO][4]) {
    float n[4][6];
    #pragma unroll
    for (int r = 0; r < 4; r++) {
        const int hh = h0 + r - 1;
        const float m_ = (((unsigned)hh < S) ? 1.f : 0.f) * md;
        const float rs = rstd * m_, nm = nmr * m_;
        n[r][0] = fwl * fmaxf(fmaf(e0[r],   rs, nm), 0.f);
        n[r][1] =       fmaxf(fmaf(f4[r].x, rs, nm), 0.f);
        n[r][2] =       fmaxf(fmaf(f4[r].y, rs, nm), 0.f);
        n[r][3] =       fmaxf(fmaf(f4[r].z, rs, nm), 0.f);
        n[r][4] =       fmaxf(fmaf(f4[r].w, rs, nm), 0.f);
        n[r][5] = fwr * fmaxf(fmaf(e1[r],   rs, nm), 0.f);
    }
    // output h0+p with tap kh reads row r = p + kh
    #pragma unroll
    for (int kh = 0; kh < 3; kh++) {
        #pragma unroll
        for (int co = 0; co < CO; co++) {
            const float* wc = TW ? (wp + kh * 24 + co * 3)
                                 : (wp + co * (CI * 81) + kh * 3);
            const float k0 = wc[0], k1 = wc[1], k2 = wc[2];
            #pragma unroll
            for (int j = 0; j < 4; j++) {
                float a0 = acc[0][co][j];
                a0 = fmaf(n[kh][j],     k0, a0);
                a0 = fmaf(n[kh][j + 1], k1, a0);
                a0 = fmaf(n[kh][j + 2], k2, a0);
                acc[0][co][j] = a0;
                float a1 = acc[1][co][j];
                a1 = fmaf(n[kh + 1][j],     k0, a1);
                a1 = fmaf(n[kh + 1][j + 1], k1, a1);
                a1 = fmaf(n[kh + 1][j + 2], k2, a1);
                acc[1][co][j] = a1;
            }
        }
    }
}

// Register-blocked fused norm+relu+conv4d with explicit kd software pipeline.
// Thread tile: 4 w (float4) x 2 h x 8 co = 64 accumulators.
// Block (24,8): 96 w x 16 h at fixed (d,t). Grid (96, 6, 8).
// kd pipeline: load kd0; prefetch kd1; compute kd0; prefetch kd2; compute kd1;
// compute kd2 — each kd's 12 row loads hide under the previous kd's 576 FMAs.
template <bool TW>
__global__ __launch_bounds__(192, 3) void conv4d_fused(
        const float* __restrict__ x, const float* __restrict__ wsrc,
        const float* __restrict__ bias, const float* __restrict__ ws,
        float* __restrict__ out) {
    const int lane = threadIdx.x;          // 0..23 -> w chunk
    const int ty   = threadIdx.y;          // 0..7
    const int w0   = lane << 2;            // 0,4,...,92
    const int d    = blockIdx.x;
    const int h0   = (blockIdx.y * 8 + ty) * 2;   // first of 2 h rows
    const int t    = blockIdx.z;

    float acc[2][CO][4];
    #pragma unroll
    for (int p = 0; p < 2; p++)
        #pragma unroll
        for (int co = 0; co < CO; co++)
            #pragma unroll
            for (int j = 0; j < 4; j++) acc[p][co][j] = 0.f;

    const bool wlb = (lane > 0), wrb = (lane < 23);
    const int  om1 = wlb ? -1 : 0;         // clamped: loads always in-range
    const int  op4 = wrb ?  4 : 3;
    const float fwl = wlb ? 1.f : 0.f, fwr = wrb ? 1.f : 0.f;
    const float inv_n = 1.f / (float)SLICE;

    const int dm1 = d > 0 ? d - 1 : 0;
    const int dp1 = d < S - 1 ? d + 1 : S - 1;
    const float md0 = d > 0 ? 1.f : 0.f;
    const float md2 = d < S - 1 ? 1.f : 0.f;

    float4 fA[4], fB[4];
    float eA0[4], eA1[4], eB0[4], eB1[4];

    for (int ci = 0; ci < CI; ci++) {
        for (int kt = 0; kt < 3; kt++) {
            const int tt = t + kt - 1;
            if ((unsigned)tt >= TT) continue;      // uniform, outer: cheap
            const int sl = ci * TT + tt;
            const float mean = ws[sl] * inv_n;
            const float var  = ws[NSLICE + sl] * inv_n - mean * mean;
            const float rstd = rsqrtf(var + EPS);
            const float nmr  = -mean * rstd;
            const float* xs = x + (size_t)sl * SLICE;
            const float* xp0 = xs + (size_t)dm1 * (S * S);
            const float* xp1 = xs + (size_t)d   * (S * S);
            const float* xp2 = xs + (size_t)dp1 * (S * S);
            const float* wp = TW ? (wsrc + (ci * 3 + kt) * 216)
                                 : (wsrc + ci * 81 + kt * 27);

            load_rows(xp0, h0, w0, om1, op4, fA, eA0, eA1);          // kd0
            load_rows(xp1, h0, w0, om1, op4, fB, eB0, eB1);          // kd1 prefetch
            compute_kd<TW>(fA, eA0, eA1, rstd, nmr, md0, h0, fwl, fwr,
                           TW ? wp : wp, acc);                        // kd0
            load_rows(xp2, h0, w0, om1, op4, fA, eA0, eA1);          // kd2 prefetch
            compute_kd<TW>(fB, eB0, eB1, rstd, nmr, 1.f, h0, fwl, fwr,
                           TW ? wp + 72 : wp + 9, acc);               // kd1
            compute_kd<TW>(fA, eA0, eA1, rstd, nmr, md2, h0, fwl, fwr,
                           TW ? wp + 144 : wp + 18, acc);             // kd2
        }
    }

    // out shape (1, CO, T, D, H, W); float4 stores (w0 is 16B-aligned)
    #pragma unroll
    for (int p = 0; p < 2; p++) {
        const size_t obase = (((size_t)t * S + d) * S + (h0 + p)) * S + w0;
        #pragma unroll
        for (int co = 0; co < CO; co++) {
            const float bb = bias[co];
            float4 o;
            o.x = acc[p][co][0] + bb;
            o.y = acc[p][co][1] + bb;
            o.z = acc[p][co][2] + bb;
            o.w = acc[p][co][3] + bb;
            *reinterpret_cast<float4*>(out + (size_t)co * ((size_t)TT * SLICE) + obase) = o;
        }
    }
}

extern "C" void kernel_launch(void* const* d_in, const int* in_sizes, int n_in,
                              void* d_out, int out_size, void* d_ws, size_t ws_size,
                              hipStream_t stream) {
    const float* x   = (const float*)d_in[0];
    const float* w   = (const float*)d_in[1];
    const float* b   = (const float*)d_in[2];
    float* out = (float*)d_out;
    float* ws  = (float*)d_ws;

    const bool tw = ws_size >= (size_t)(WS_WT_OFF + WTOT) * sizeof(float);

    // zero the atomic accumulators (ws is poisoned before every launch)
    hipMemsetAsync(ws, 0, 2 * NSLICE * sizeof(float), stream);
    stats_partial<<<dim3(64, NSLICE), 256, 0, stream>>>(x, ws);
    if (tw) {
        wtranspose<<<(WTOT + 255) / 256, 256, 0, stream>>>(w, ws + WS_WT_OFF);
        conv4d_fused<true><<<dim3(S, S / 16, TT), dim3(24, 8, 1), 0, stream>>>(
                x, ws + WS_WT_OFF, b, ws, out);
    } else {
        conv4d_fused<false><<<dim3(S, S / 16, TT), dim3(24, 8, 1), 0, stream>>>(
                x, w, b, ws, out);
    }
}

// Round 4
// 656.861 us; speedup vs baseline: 1.1991x; 1.1991x over previous
//
#include <hip/hip_runtime.h>

#define CI 4
#define CO 8
#define TT 8
#define S 96
#define S2 (S*S)
#define SLICE (S*S*S)          // 884736 elements per (c,t) slice
#define NSLICE (CI*TT)         // 32 slices
#define EPS 1e-5f
#define WTOT (CO*CI*81)        // 10368 weight elements
#define WS_WT_OFF 64           // float offset of transposed weights in ws

// ws layout (floats): [0:32) sum, [32:64) sumsq, [64:64+WTOT) transposed weights

__global__ __launch_bounds__(256) void stats_partial(
        const float* __restrict__ x, float* __restrict__ ws) {
    const int slice = blockIdx.y;
    const float4* p = reinterpret_cast<const float4*>(x + (size_t)slice * SLICE);
    const int n4 = SLICE / 4;  // 221184
    float s = 0.f, ss = 0.f;
    for (int i = blockIdx.x * blockDim.x + threadIdx.x; i < n4;
         i += gridDim.x * blockDim.x) {
        float4 v = p[i];
        s  += v.x + v.y + v.z + v.w;
        ss += v.x*v.x + v.y*v.y + v.z*v.z + v.w*v.w;
    }
    #pragma unroll
    for (int off = 32; off > 0; off >>= 1) {
        s  += __shfl_down(s, off);
        ss += __shfl_down(ss, off);
    }
    __shared__ float ls[4], lss[4];
    const int lane = threadIdx.x & 63, wid = threadIdx.x >> 6;
    if (lane == 0) { ls[wid] = s; lss[wid] = ss; }
    __syncthreads();
    if (threadIdx.x == 0) {
        float ts  = ls[0] + ls[1] + ls[2] + ls[3];
        float tss = lss[0] + lss[1] + lss[2] + lss[3];
        atomicAdd(&ws[slice], ts);
        atomicAdd(&ws[NSLICE + slice], tss);
    }
}

// Transpose weights (CO,CI,3,3,3,3) -> [ci][kt][kd][kh][co][kw] so each
// (kd,kh) tap group is 24 contiguous floats (96 B) => wide s_loads.
__global__ void wtranspose(const float* __restrict__ w, float* __restrict__ wt) {
    int i = blockIdx.x * blockDim.x + threadIdx.x;
    if (i >= WTOT) return;
    int kw = i % 3; int r = i / 3;
    int co = r % CO; r /= CO;
    int kh = r % 3;  r /= 3;
    int kd = r % 3;  r /= 3;
    int kt = r % 3;  r /= 3;
    int ci = r;
    wt[i] = w[((((co * CI + ci) * 3 + kt) * 3 + kd) * 3 + kh) * 3 + kw];
}

// Register-blocked fused norm+relu+conv4d, software-pipelined over the
// flattened (ci,kt,kd) stage sequence with 3 rotating NAMED register buffers
// (A,B,C) — no arrays passed to functions (R3's scratch-spill lesson).
// Thread tile: 4 w (float4) x 2 h x 8 co = 64 accumulators.
// Block (24,8): 96 w x 16 h at fixed (d,t). Grid (96, 6, 8).
// Every row-load group is issued one full 576-FMA compute block before use.
template <bool TW>
__global__ __launch_bounds__(192, 3) void conv4d_fused(
        const float* __restrict__ x, const float* __restrict__ wsrc,
        const float* __restrict__ bias, const float* __restrict__ ws,
        float* __restrict__ out) {
    const int lane = threadIdx.x;          // 0..23 -> w chunk
    const int ty   = threadIdx.y;          // 0..7
    const int w0   = lane << 2;            // 0,4,...,92
    const int d    = blockIdx.x;
    const int h0   = (blockIdx.y * 8 + ty) * 2;   // first of 2 h rows
    const int t    = blockIdx.z;

    float acc[2][CO][4];
    #pragma unroll
    for (int p = 0; p < 2; p++)
        #pragma unroll
        for (int co = 0; co < CO; co++)
            #pragma unroll
            for (int j = 0; j < 4; j++) acc[p][co][j] = 0.f;

    const bool wlb = (lane > 0), wrb = (lane < 23);
    const int  om1 = wlb ? -1 : 0;         // clamped: loads always in-range
    const int  op4 = wrb ?  4 : 3;
    const float fwl = wlb ? 1.f : 0.f, fwr = wrb ? 1.f : 0.f;
    const float inv_n = 1.f / (float)SLICE;

    // d-edge (uniform per block) and h-edge (per thread) masks/clamps, hoisted
    const int dm1 = d > 0 ? d - 1 : 0;
    const int dp1 = d < S - 1 ? d + 1 : S - 1;
    const float md0 = d > 0 ? 1.f : 0.f;
    const float md2 = d < S - 1 ? 1.f : 0.f;
    int   off[4];   // row offsets within a d-slice (h-clamped), compile-time idx only
    float mr0, mr1, mr2, mr3;
    {
        const int hh0 = h0 - 1, hh1 = h0, hh2 = h0 + 1, hh3 = h0 + 2;
        mr0 = ((unsigned)hh0 < S) ? 1.f : 0.f;
        mr1 = 1.f; mr2 = 1.f;
        mr3 = ((unsigned)hh3 < S) ? 1.f : 0.f;
        const int hc0 = hh0 < 0 ? 0 : hh0;
        const int hc3 = hh3 > S - 1 ? S - 1 : hh3;
        off[0] = hc0 * S + w0; off[1] = hh1 * S + w0;
        off[2] = hh2 * S + w0; off[3] = hc3 * S + w0;
    }
    const int o0 = off[0], o1 = off[1], o2 = off[2], o3 = off[3];

    // kt range for this t (uniform): tt = t+kt-1 in [0,TT)
    const int ktlo = (t == 0) ? 1 : 0;
    const int kthi = (t == TT - 1) ? 1 : 2;
    const int nkt  = kthi - ktlo + 1;
    const int niter = CI * nkt;

    // ---- named register buffers (12 values each) ----
    #define DECL_BUF(N) \
        float4 f##N##0, f##N##1, f##N##2, f##N##3; \
        float e##N##00, e##N##01, e##N##02, e##N##03; \
        float e##N##10, e##N##11, e##N##12, e##N##13;
    DECL_BUF(A) DECL_BUF(B) DECL_BUF(C)

    #define LOAD_BUF(N, XP) do { \
        const float* _r0 = (XP) + o0; const float* _r1 = (XP) + o1; \
        const float* _r2 = (XP) + o2; const float* _r3 = (XP) + o3; \
        f##N##0 = *reinterpret_cast<const float4*>(_r0); \
        f##N##1 = *reinterpret_cast<const float4*>(_r1); \
        f##N##2 = *reinterpret_cast<const float4*>(_r2); \
        f##N##3 = *reinterpret_cast<const float4*>(_r3); \
        e##N##00 = _r0[om1]; e##N##01 = _r1[om1]; \
        e##N##02 = _r2[om1]; e##N##03 = _r3[om1]; \
        e##N##10 = _r0[op4]; e##N##11 = _r1[op4]; \
        e##N##12 = _r2[op4]; e##N##13 = _r3[op4]; \
    } while (0)

    #define NORM_ROW(N, R, MR, MD) do { \
        const float m_ = (MR) * (MD); \
        const float rs = rstd * m_, nm = nmr * m_; \
        nn[R][0] = fwl * fmaxf(fmaf(e##N##0##R, rs, nm), 0.f); \
        nn[R][1] =       fmaxf(fmaf(f##N##R.x,  rs, nm), 0.f); \
        nn[R][2] =       fmaxf(fmaf(f##N##R.y,  rs, nm), 0.f); \
        nn[R][3] =       fmaxf(fmaf(f##N##R.z,  rs, nm), 0.f); \
        nn[R][4] =       fmaxf(fmaf(f##N##R.w,  rs, nm), 0.f); \
        nn[R][5] = fwr * fmaxf(fmaf(e##N##1##R, rs, nm), 0.f); \
    } while (0)

    // output h0+p with tap kh reads row r = p + kh
    #define COMPUTE_BUF(N, WP, MD) do { \
        float nn[4][6]; \
        NORM_ROW(N, 0, mr0, MD); NORM_ROW(N, 1, mr1, MD); \
        NORM_ROW(N, 2, mr2, MD); NORM_ROW(N, 3, mr3, MD); \
        _Pragma("unroll") \
        for (int kh = 0; kh < 3; kh++) { \
            _Pragma("unroll") \
            for (int co = 0; co < CO; co++) { \
                const float* wc = TW ? ((WP) + kh * 24 + co * 3) \
                                     : ((WP) + co * (CI * 81) + kh * 3); \
                const float k0 = wc[0], k1 = wc[1], k2 = wc[2]; \
                _Pragma("unroll") \
                for (int j = 0; j < 4; j++) { \
                    float a0 = acc[0][co][j]; \
                    a0 = fmaf(nn[kh][j],     k0, a0); \
                    a0 = fmaf(nn[kh][j + 1], k1, a0); \
                    a0 = fmaf(nn[kh][j + 2], k2, a0); \
                    acc[0][co][j] = a0; \
                    float a1 = acc[1][co][j]; \
                    a1 = fmaf(nn[kh + 1][j],     k0, a1); \
                    a1 = fmaf(nn[kh + 1][j + 1], k1, a1); \
                    a1 = fmaf(nn[kh + 1][j + 2], k2, a1); \
                    acc[1][co][j] = a1; \
                } \
            } \
        } \
    } while (0)

    // ---- prologue: params + first two stage loads for (ci=0, kt=ktlo) ----
    int ci = 0, kt = ktlo;
    int sl = ci * TT + (t + kt - 1);
    const float* xs = x + (size_t)sl * SLICE;
    const float* xp2;
    float rstd, nmr;
    {
        const float mean = ws[sl] * inv_n;
        const float var  = ws[NSLICE + sl] * inv_n - mean * mean;
        rstd = rsqrtf(var + EPS);
        nmr  = -mean * rstd;
    }
    const float* wp = TW ? (wsrc + (ci * 3 + kt) * 216)
                         : (wsrc + ci * 81 + kt * 27);
    xp2 = xs + (size_t)dp1 * S2;
    LOAD_BUF(A, xs + (size_t)dm1 * S2);   // kd0
    LOAD_BUF(B, xs + (size_t)d   * S2);   // kd1

    for (int it = 0; it < niter; it++) {
        LOAD_BUF(C, xp2);                                  // kd2 of current

        COMPUTE_BUF(A, TW ? wp : wp, md0);                 // kd0

        // advance (uniform scalar); clamp at the end (loads wasted, unread)
        int kt_n = kt, ci_n = ci;
        if (it + 1 < niter) {
            kt_n = kt + 1;
            if (kt_n > kthi) { kt_n = ktlo; ci_n = ci + 1; }
        }
        const int sl_n = ci_n * TT + (t + kt_n - 1);
        const float* xs_n = x + (size_t)sl_n * SLICE;
        const float mean_n = ws[sl_n] * inv_n;
        const float var_n  = ws[NSLICE + sl_n] * inv_n - mean_n * mean_n;
        const float rstd_n = rsqrtf(var_n + EPS);
        const float nmr_n  = -mean_n * rstd_n;
        const float* wp_n = TW ? (wsrc + (ci_n * 3 + kt_n) * 216)
                               : (wsrc + ci_n * 81 + kt_n * 27);

        LOAD_BUF(A, xs_n + (size_t)dm1 * S2);              // next kd0

        COMPUTE_BUF(B, TW ? wp + 72 : wp + 9, 1.f);        // kd1

        LOAD_BUF(B, xs_n + (size_t)d * S2);                // next kd1

        COMPUTE_BUF(C, TW ? wp + 144 : wp + 18, md2);      // kd2

        // rotate params
        rstd = rstd_n; nmr = nmr_n; wp = wp_n;
        xp2 = xs_n + (size_t)dp1 * S2;
        ci = ci_n; kt = kt_n;
    }

    #undef DECL_BUF
    #undef LOAD_BUF
    #undef NORM_ROW
    #undef COMPUTE_BUF

    // out shape (1, CO, T, D, H, W); float4 stores (w0 is 16B-aligned)
    #pragma unroll
    for (int p = 0; p < 2; p++) {
        const size_t obase = (((size_t)t * S + d) * S + (h0 + p)) * S + w0;
        #pragma unroll
        for (int co = 0; co < CO; co++) {
            const float bb = bias[co];
            float4 o;
            o.x = acc[p][co][0] + bb;
            o.y = acc[p][co][1] + bb;
            o.z = acc[p][co][2] + bb;
            o.w = acc[p][co][3] + bb;
            *reinterpret_cast<float4*>(out + (size_t)co * ((size_t)TT * SLICE) + obase) = o;
        }
    }
}

extern "C" void kernel_launch(void* const* d_in, const int* in_sizes, int n_in,
                              void* d_out, int out_size, void* d_ws, size_t ws_size,
                              hipStream_t stream) {
    const float* x   = (const float*)d_in[0];
    const float* w   = (const float*)d_in[1];
    const float* b   = (const float*)d_in[2];
    float* out = (float*)d_out;
    float* ws  = (float*)d_ws;

    const bool tw = ws_size >= (size_t)(WS_WT_OFF + WTOT) * sizeof(float);

    // zero the atomic accumulators (ws is poisoned before every launch)
    hipMemsetAsync(ws, 0, 2 * NSLICE * sizeof(float), stream);
    stats_partial<<<dim3(64, NSLICE), 256, 0, stream>>>(x, ws);
    if (tw) {
        wtranspose<<<(WTOT + 255) / 256, 256, 0, stream>>>(w, ws + WS_WT_OFF);
        conv4d_fused<true><<<dim3(S, S / 16, TT), dim3(24, 8, 1), 0, stream>>>(
                x, ws + WS_WT_OFF, b, ws, out);
    } else {
        conv4d_fused<false><<<dim3(S, S / 16, TT), dim3(24, 8, 1), 0, stream>>>(
                x, w, b, ws, out);
    }
}

// Round 5
// 648.738 us; speedup vs baseline: 1.2141x; 1.0125x over previous
//
#include <hip/hip_runtime.h>

#define CI 4
#define CO 8
#define TT 8
#define S 96
#define S2 (S*S)
#define SLICE (S*S*S)          // 884736 elements per (c,t) slice
#define NSLICE (CI*TT)         // 32 slices
#define EPS 1e-5f
#define WTOT (CO*CI*81)        // 10368 weight elements
#define WS_WT_OFF 64           // float offset of transposed weights in ws

// ws layout (floats): [0:32) sum, [32:64) sumsq, [64:64+WTOT) transposed weights

__global__ __launch_bounds__(256) void stats_partial(
        const float* __restrict__ x, float* __restrict__ ws) {
    const int slice = blockIdx.y;
    const float4* p = reinterpret_cast<const float4*>(x + (size_t)slice * SLICE);
    const int n4 = SLICE / 4;  // 221184
    float s = 0.f, ss = 0.f;
    for (int i = blockIdx.x * blockDim.x + threadIdx.x; i < n4;
         i += gridDim.x * blockDim.x) {
        float4 v = p[i];
        s  += v.x + v.y + v.z + v.w;
        ss += v.x*v.x + v.y*v.y + v.z*v.z + v.w*v.w;
    }
    #pragma unroll
    for (int off = 32; off > 0; off >>= 1) {
        s  += __shfl_down(s, off);
        ss += __shfl_down(ss, off);
    }
    __shared__ float ls[4], lss[4];
    const int lane = threadIdx.x & 63, wid = threadIdx.x >> 6;
    if (lane == 0) { ls[wid] = s; lss[wid] = ss; }
    __syncthreads();
    if (threadIdx.x == 0) {
        float ts  = ls[0] + ls[1] + ls[2] + ls[3];
        float tss = lss[0] + lss[1] + lss[2] + lss[3];
        atomicAdd(&ws[slice], ts);
        atomicAdd(&ws[NSLICE + slice], tss);
    }
}

// Transpose weights (CO,CI,3,3,3,3) -> [ci][kt][kd][kh][co][kw] so each
// (kd,kh) tap group is 24 contiguous floats (96 B) => wide s_loads.
__global__ void wtranspose(const float* __restrict__ w, float* __restrict__ wt) {
    int i = blockIdx.x * blockDim.x + threadIdx.x;
    if (i >= WTOT) return;
    int kw = i % 3; int r = i / 3;
    int co = r % CO; r /= CO;
    int kh = r % 3;  r /= 3;
    int kd = r % 3;  r /= 3;
    int kt = r % 3;  r /= 3;
    int ci = r;
    wt[i] = w[((((co * CI + ci) * 3 + kt) * 3 + kd) * 3 + kh) * 3 + kw];
}

// Register-blocked fused norm+relu+conv4d, software-pipelined over the
// flattened (ci,kt,kd) stage sequence with 3 rotating NAMED register buffers.
// vs R4: TAP loops reordered weight-tap-major (kh -> q -> co -> j -> P) so
// consecutive FMAs never share an accumulator (dep reuse distance = 64 FMAs
// instead of 1; v_fma dep latency ~4cyc was the remaining ~20% stall theory).
// Per-accumulator summation order unchanged (k0,k1,k2 within each kh) ->
// bit-identical to R4.
template <bool TW>
__global__ __launch_bounds__(192, 3) void conv4d_fused(
        const float* __restrict__ x, const float* __restrict__ wsrc,
        const float* __restrict__ bias, const float* __restrict__ ws,
        float* __restrict__ out) {
    const int lane = threadIdx.x;          // 0..23 -> w chunk
    const int ty   = threadIdx.y;          // 0..7
    const int w0   = lane << 2;            // 0,4,...,92
    const int d    = blockIdx.x;
    const int h0   = (blockIdx.y * 8 + ty) * 2;   // first of 2 h rows
    const int t    = blockIdx.z;

    float acc[2][CO][4];
    #pragma unroll
    for (int p = 0; p < 2; p++)
        #pragma unroll
        for (int co = 0; co < CO; co++)
            #pragma unroll
            for (int j = 0; j < 4; j++) acc[p][co][j] = 0.f;

    const bool wlb = (lane > 0), wrb = (lane < 23);
    const int  om1 = wlb ? -1 : 0;         // clamped: loads always in-range
    const int  op4 = wrb ?  4 : 3;
    const float fwl = wlb ? 1.f : 0.f, fwr = wrb ? 1.f : 0.f;
    const float inv_n = 1.f / (float)SLICE;

    // d-edge (uniform per block) and h-edge (per thread) masks/clamps, hoisted
    const int dm1 = d > 0 ? d - 1 : 0;
    const int dp1 = d < S - 1 ? d + 1 : S - 1;
    const float md0 = d > 0 ? 1.f : 0.f;
    const float md2 = d < S - 1 ? 1.f : 0.f;
    float mr0, mr1, mr2, mr3;
    int o0, o1, o2, o3;
    {
        const int hh0 = h0 - 1, hh3 = h0 + 2;
        mr0 = ((unsigned)hh0 < S) ? 1.f : 0.f;
        mr1 = 1.f; mr2 = 1.f;
        mr3 = ((unsigned)hh3 < S) ? 1.f : 0.f;
        const int hc0 = hh0 < 0 ? 0 : hh0;
        const int hc3 = hh3 > S - 1 ? S - 1 : hh3;
        o0 = hc0 * S + w0; o1 = h0 * S + w0;
        o2 = (h0 + 1) * S + w0; o3 = hc3 * S + w0;
    }

    // kt range for this t (uniform): tt = t+kt-1 in [0,TT)
    const int ktlo = (t == 0) ? 1 : 0;
    const int kthi = (t == TT - 1) ? 1 : 2;
    const int nkt  = kthi - ktlo + 1;
    const int niter = CI * nkt;

    // ---- named register buffers (12 values each) ----
    #define DECL_BUF(N) \
        float4 f##N##0, f##N##1, f##N##2, f##N##3; \
        float e##N##00, e##N##01, e##N##02, e##N##03; \
        float e##N##10, e##N##11, e##N##12, e##N##13;
    DECL_BUF(A) DECL_BUF(B) DECL_BUF(C)

    #define LOAD_BUF(N, XP) do { \
        const float* _r0 = (XP) + o0; const float* _r1 = (XP) + o1; \
        const float* _r2 = (XP) + o2; const float* _r3 = (XP) + o3; \
        f##N##0 = *reinterpret_cast<const float4*>(_r0); \
        f##N##1 = *reinterpret_cast<const float4*>(_r1); \
        f##N##2 = *reinterpret_cast<const float4*>(_r2); \
        f##N##3 = *reinterpret_cast<const float4*>(_r3); \
        e##N##00 = _r0[om1]; e##N##01 = _r1[om1]; \
        e##N##02 = _r2[om1]; e##N##03 = _r3[om1]; \
        e##N##10 = _r0[op4]; e##N##11 = _r1[op4]; \
        e##N##12 = _r2[op4]; e##N##13 = _r3[op4]; \
    } while (0)

    #define NORM_ROW(N, R, MR, MD) do { \
        const float m_ = (MR) * (MD); \
        const float rs = rstd * m_, nm = nmr * m_; \
        nn[R][0] = fwl * fmaxf(fmaf(e##N##0##R, rs, nm), 0.f); \
        nn[R][1] =       fmaxf(fmaf(f##N##R.x,  rs, nm), 0.f); \
        nn[R][2] =       fmaxf(fmaf(f##N##R.y,  rs, nm), 0.f); \
        nn[R][3] =       fmaxf(fmaf(f##N##R.z,  rs, nm), 0.f); \
        nn[R][4] =       fmaxf(fmaf(f##N##R.w,  rs, nm), 0.f); \
        nn[R][5] = fwr * fmaxf(fmaf(e##N##1##R, rs, nm), 0.f); \
    } while (0)

    // output h0+p with tap kh reads row r = p + kh.
    // q-major: per (kh,q) pass, touch all 64 accs once (no back-to-back dep).
    // Per-acc order within kh is still q=0,1,2 => identical summation order.
    #define COMPUTE_BUF(N, WP, MD) do { \
        float nn[4][6]; \
        NORM_ROW(N, 0, mr0, MD); NORM_ROW(N, 1, mr1, MD); \
        NORM_ROW(N, 2, mr2, MD); NORM_ROW(N, 3, mr3, MD); \
        _Pragma("unroll") \
        for (int kh = 0; kh < 3; kh++) { \
            _Pragma("unroll") \
            for (int q = 0; q < 3; q++) { \
                _Pragma("unroll") \
                for (int co = 0; co < CO; co++) { \
                    const float k_ = TW ? (WP)[kh * 24 + co * 3 + q] \
                                        : (WP)[co * (CI * 81) + kh * 3 + q]; \
                    _Pragma("unroll") \
                    for (int j = 0; j < 4; j++) { \
                        acc[0][co][j] = fmaf(nn[kh][j + q],     k_, acc[0][co][j]); \
                        acc[1][co][j] = fmaf(nn[kh + 1][j + q], k_, acc[1][co][j]); \
                    } \
                } \
            } \
        } \
    } while (0)

    // ---- prologue: params + first two stage loads for (ci=0, kt=ktlo) ----
    int ci = 0, kt = ktlo;
    int sl = ci * TT + (t + kt - 1);
    const float* xs = x + (size_t)sl * SLICE;
    const float* xp2;
    float rstd, nmr;
    {
        const float mean = ws[sl] * inv_n;
        const float var  = ws[NSLICE + sl] * inv_n - mean * mean;
        rstd = rsqrtf(var + EPS);
        nmr  = -mean * rstd;
    }
    const float* wp = TW ? (wsrc + (ci * 3 + kt) * 216)
                         : (wsrc + ci * 81 + kt * 27);
    xp2 = xs + (size_t)dp1 * S2;
    LOAD_BUF(A, xs + (size_t)dm1 * S2);   // kd0
    LOAD_BUF(B, xs + (size_t)d   * S2);   // kd1

    for (int it = 0; it < niter; it++) {
        LOAD_BUF(C, xp2);                                  // kd2 of current

        COMPUTE_BUF(A, wp, md0);                           // kd0

        // advance (uniform scalar); clamp at the end (loads wasted, unread)
        int kt_n = kt, ci_n = ci;
        if (it + 1 < niter) {
            kt_n = kt + 1;
            if (kt_n > kthi) { kt_n = ktlo; ci_n = ci + 1; }
        }
        const int sl_n = ci_n * TT + (t + kt_n - 1);
        const float* xs_n = x + (size_t)sl_n * SLICE;
        const float mean_n = ws[sl_n] * inv_n;
        const float var_n  = ws[NSLICE + sl_n] * inv_n - mean_n * mean_n;
        const float rstd_n = rsqrtf(var_n + EPS);
        const float nmr_n  = -mean_n * rstd_n;
        const float* wp_n = TW ? (wsrc + (ci_n * 3 + kt_n) * 216)
                               : (wsrc + ci_n * 81 + kt_n * 27);

        LOAD_BUF(A, xs_n + (size_t)dm1 * S2);              // next kd0

        COMPUTE_BUF(B, TW ? wp + 72 : wp + 9, 1.f);        // kd1

        LOAD_BUF(B, xs_n + (size_t)d * S2);                // next kd1

        COMPUTE_BUF(C, TW ? wp + 144 : wp + 18, md2);      // kd2

        // rotate params
        rstd = rstd_n; nmr = nmr_n; wp = wp_n;
        xp2 = xs_n + (size_t)dp1 * S2;
        ci = ci_n; kt = kt_n;
    }

    #undef DECL_BUF
    #undef LOAD_BUF
    #undef NORM_ROW
    #undef COMPUTE_BUF

    // out shape (1, CO, T, D, H, W); float4 stores (w0 is 16B-aligned)
    #pragma unroll
    for (int p = 0; p < 2; p++) {
        const size_t obase = (((size_t)t * S + d) * S + (h0 + p)) * S + w0;
        #pragma unroll
        for (int co = 0; co < CO; co++) {
            const float bb = bias[co];
            float4 o;
            o.x = acc[p][co][0] + bb;
            o.y = acc[p][co][1] + bb;
            o.z = acc[p][co][2] + bb;
            o.w = acc[p][co][3] + bb;
            *reinterpret_cast<float4*>(out + (size_t)co * ((size_t)TT * SLICE) + obase) = o;
        }
    }
}

extern "C" void kernel_launch(void* const* d_in, const int* in_sizes, int n_in,
                              void* d_out, int out_size, void* d_ws, size_t ws_size,
                              hipStream_t stream) {
    const float* x   = (const float*)d_in[0];
    const float* w   = (const float*)d_in[1];
    const float* b   = (const float*)d_in[2];
    float* out = (float*)d_out;
    float* ws  = (float*)d_ws;

    const bool tw = ws_size >= (size_t)(WS_WT_OFF + WTOT) * sizeof(float);

    // zero the atomic accumulators (ws is poisoned before every launch)
    hipMemsetAsync(ws, 0, 2 * NSLICE * sizeof(float), stream);
    stats_partial<<<dim3(64, NSLICE), 256, 0, stream>>>(x, ws);
    if (tw) {
        wtranspose<<<(WTOT + 255) / 256, 256, 0, stream>>>(w, ws + WS_WT_OFF);
        conv4d_fused<true><<<dim3(S, S / 16, TT), dim3(24, 8, 1), 0, stream>>>(
                x, ws + WS_WT_OFF, b, ws, out);
    } else {
        conv4d_fused<false><<<dim3(S, S / 16, TT), dim3(24, 8, 1), 0, stream>>>(
                x, w, b, ws, out);
    }
}